// Round 8
// baseline (98.686 us; speedup 1.0000x reference)
//
#include <hip/hip_runtime.h>

#define D 128
#define NB2MAX 512   // max scan blocks at 512 nodes/block (n <= 262144)

typedef __attribute__((ext_vector_type(8))) short bf16x8;
typedef __attribute__((ext_vector_type(4))) float f32x4;

__device__ __forceinline__ unsigned short f2bf(float f) {
    unsigned int u = __float_as_uint(f);
    unsigned int r = (u + 0x7fffu + ((u >> 16) & 1u)) >> 16;
    return (unsigned short)r;
}
__device__ __forceinline__ float bf_lo(unsigned int u) { return __uint_as_float(u << 16); }
__device__ __forceinline__ float bf_hi(unsigned int u) { return __uint_as_float(u & 0xffff0000u); }

// ---------------- fused stage kernel ----------------
// blocks [0,pre): preprocessing stage selected by `mode`
//   mode 0: zero cnt (workN = n)
//   mode 1: count degrees + record slots, int4 (workN = e4)
//   mode 2: block-local excl scan of cnt (512/node-block) + dinv (workN = n)
//   mode 3: single-block excl scan of bsum -> bscan (nb2 entries)
// blocks [pre, ...): bf16 MFMA gemm  h = bf16(x @ W), row chunk at (goff+bid-pre)*128
__global__ __launch_bounds__(512) void k_stage(int mode, int pre, int goff, int workN,
                                               int* __restrict__ cnt, int* __restrict__ slot,
                                               const int* __restrict__ dstv,
                                               int* __restrict__ off, int* __restrict__ bsum,
                                               float* __restrict__ dinv, int* __restrict__ bscan,
                                               int nb2,
                                               const float* __restrict__ x,
                                               const float* __restrict__ W,
                                               unsigned short* __restrict__ h, int n) {
    __shared__ __align__(16) unsigned short Wt[D * D];  // 32 KB (gemm branch)
    __shared__ int s[512];                              // scan branch
    int t = threadIdx.x;
    int bid = blockIdx.x;

    if (bid < pre) {
        if (mode == 0) {
            int i = bid * 512 + t;
            int n4 = workN >> 2;
            if (i < n4) ((int4*)cnt)[i] = make_int4(0, 0, 0, 0);
            int rem = workN & 3;
            if (rem && i < rem) cnt[n4 * 4 + i] = 0;
        } else if (mode == 1) {
            int i = bid * 512 + t;
            if (i < workN) {
                int4 d = ((const int4*)dstv)[i];
                int s0 = atomicAdd(&cnt[d.x], 1);
                int s1 = atomicAdd(&cnt[d.y], 1);
                int s2 = atomicAdd(&cnt[d.z], 1);
                int s3 = atomicAdd(&cnt[d.w], 1);
                ((int4*)slot)[i] = make_int4(s0, s1, s2, s3);
            }
        } else if (mode == 2) {
            int i = bid * 512 + t;
            int v = (i < workN) ? cnt[i] : 0;
            if (i < workN) dinv[i] = rsqrtf((float)(v + 1));
            s[t] = v;
            __syncthreads();
            for (int d2 = 1; d2 < 512; d2 <<= 1) {
                int add = (t >= d2) ? s[t - d2] : 0;
                __syncthreads();
                s[t] += add;
                __syncthreads();
            }
            if (i < workN) off[i] = s[t] - v;      // block-local exclusive
            if (t == 511) bsum[bid] = s[511];
        } else {
            int v = (t < nb2) ? bsum[t] : 0;
            s[t] = v;
            __syncthreads();
            for (int d2 = 1; d2 < 512; d2 <<= 1) {
                int add = (t >= d2) ? s[t - d2] : 0;
                __syncthreads();
                s[t] += add;
                __syncthreads();
            }
            if (t < nb2) bscan[t] = s[t] - v;
        }
        return;
    }

    // -------- gemm branch: h = bf16(x @ W) (no dinv dependency) --------
    int gbi = goff + bid - pre;
#pragma unroll
    for (int i2 = 0; i2 < 32; ++i2) {
        int e = t + i2 * 512;
        int k = e >> 7, nn = e & 127;
        Wt[nn * D + (k ^ ((nn & 7) << 3))] = f2bf(W[e]);
    }
    __syncthreads();

    int wave = t >> 6, lane = t & 63;
    int lr = lane & 15;
    int lk = (lane >> 4) << 3;
    int row = gbi * 128 + wave * 16 + lr;
    int rclamp = row < n ? row : n - 1;

    bf16x8 afrag[4];
    const float* xr = x + (size_t)rclamp * D;
#pragma unroll
    for (int kt = 0; kt < 4; ++kt) {
        int k0 = kt * 32 + lk;
        float4 lo = *(const float4*)(xr + k0);
        float4 hi = *(const float4*)(xr + k0 + 4);
        bf16x8 a;
        a[0] = f2bf(lo.x); a[1] = f2bf(lo.y); a[2] = f2bf(lo.z); a[3] = f2bf(lo.w);
        a[4] = f2bf(hi.x); a[5] = f2bf(hi.y); a[6] = f2bf(hi.z); a[7] = f2bf(hi.w);
        afrag[kt] = a;
    }

    int orow0 = gbi * 128 + wave * 16 + ((lane >> 4) << 2);
#pragma unroll
    for (int c = 0; c < 8; ++c) {
        f32x4 acc = {0.f, 0.f, 0.f, 0.f};
        int col = c * 16 + lr;
#pragma unroll
        for (int kt = 0; kt < 4; ++kt) {
            int k0 = kt * 32 + lk;
            bf16x8 bfr = *(const bf16x8*)&Wt[col * D + (k0 ^ ((col & 7) << 3))];
            acc = __builtin_amdgcn_mfma_f32_16x16x32_bf16(afrag[kt], bfr, acc, 0, 0, 0);
        }
#pragma unroll
        for (int r = 0; r < 4; ++r) {
            int orow = orow0 + r;
            if (orow < n) h[(size_t)orow * D + col] = f2bf(acc[r]);
        }
    }
}

// ---------------- permute: ssrc2[p] = (src, dinv[src]) ----------------

__global__ __launch_bounds__(512) void k_permw_v4(const int* __restrict__ src,
                                                  const int* __restrict__ dst,
                                                  const int* __restrict__ off,
                                                  const int* __restrict__ bscan,
                                                  const int* __restrict__ slot,
                                                  const float* __restrict__ dinv,
                                                  int2* __restrict__ ssrc2, int e4) {
    int i = blockIdx.x * 512 + threadIdx.x;
    if (i < e4) {
        int4 sv = ((const int4*)src)[i];
        int4 d  = ((const int4*)dst)[i];
        int4 sl = ((const int4*)slot)[i];
        ssrc2[bscan[d.x >> 9] + off[d.x] + sl.x] = make_int2(sv.x, __float_as_int(dinv[sv.x]));
        ssrc2[bscan[d.y >> 9] + off[d.y] + sl.y] = make_int2(sv.y, __float_as_int(dinv[sv.y]));
        ssrc2[bscan[d.z >> 9] + off[d.z] + sl.z] = make_int2(sv.z, __float_as_int(dinv[sv.z]));
        ssrc2[bscan[d.w >> 9] + off[d.w] + sl.w] = make_int2(sv.w, __float_as_int(dinv[sv.w]));
    }
}

__global__ void k_count_s(const int* dst, int* cnt, int* slot, int e) {
    int i = blockIdx.x * blockDim.x + threadIdx.x;
    if (i < e) slot[i] = atomicAdd(&cnt[dst[i]], 1);
}

__global__ void k_permw_s(const int* src, const int* dst, const int* off,
                          const int* bscan, const int* slot, const float* dinv,
                          int2* ssrc2, int e) {
    int i = blockIdx.x * blockDim.x + threadIdx.x;
    if (i < e) {
        int d = dst[i], sv = src[i];
        ssrc2[bscan[d >> 9] + off[d] + slot[i]] = make_int2(sv, __float_as_int(dinv[sv]));
    }
}

// ---------------- gather: out = relu(di*(di*h_self + sum w_j*h_j) + b) ----------

__global__ __launch_bounds__(256) void k_gather4(const unsigned short* __restrict__ h,
                                                 const float* __restrict__ dinv,
                                                 const int* __restrict__ off,
                                                 const int* __restrict__ cnt,
                                                 const int* __restrict__ bscan,
                                                 const int2* __restrict__ ssrc2,
                                                 const float* __restrict__ b,
                                                 float* __restrict__ out, int n) {
    int gid = blockIdx.x * 256 + threadIdx.x;
    int node = gid >> 4;           // 16 lanes per node
    int li = gid & 15;             // covers cols li*8 .. li*8+7
    if (node >= n) return;
    float di = dinv[node];
    const uint4* h4 = (const uint4*)h;      // one row = 16 uint4
    uint4 u = h4[(size_t)node * 16 + li];
    float acc[8];
    acc[0] = di * bf_lo(u.x); acc[1] = di * bf_hi(u.x);
    acc[2] = di * bf_lo(u.y); acc[3] = di * bf_hi(u.y);
    acc[4] = di * bf_lo(u.z); acc[5] = di * bf_hi(u.z);
    acc[6] = di * bf_lo(u.w); acc[7] = di * bf_hi(u.w);

    int m = cnt[node];
    int s0 = bscan[node >> 9] + off[node];

    for (int j = 0; j < m; j += 8) {
        uint4 v[8];
        float w[8];
#pragma unroll
        for (int k = 0; k < 8; ++k) {
            int jk = j + k;
            int idx = jk < m ? jk : m - 1;
            int2 sw = ssrc2[s0 + idx];
            v[k] = h4[(size_t)sw.x * 16 + li];
            w[k] = jk < m ? __int_as_float(sw.y) : 0.f;
        }
#pragma unroll
        for (int k = 0; k < 8; ++k) {
            acc[0] = fmaf(w[k], bf_lo(v[k].x), acc[0]);
            acc[1] = fmaf(w[k], bf_hi(v[k].x), acc[1]);
            acc[2] = fmaf(w[k], bf_lo(v[k].y), acc[2]);
            acc[3] = fmaf(w[k], bf_hi(v[k].y), acc[3]);
            acc[4] = fmaf(w[k], bf_lo(v[k].z), acc[4]);
            acc[5] = fmaf(w[k], bf_hi(v[k].z), acc[5]);
            acc[6] = fmaf(w[k], bf_lo(v[k].w), acc[6]);
            acc[7] = fmaf(w[k], bf_hi(v[k].w), acc[7]);
        }
    }

    const float4* b4 = (const float4*)b;
    float4 bb0 = b4[li * 2], bb1 = b4[li * 2 + 1];
    float4 o0, o1;
    o0.x = fmaxf(fmaf(di, acc[0], bb0.x), 0.f);
    o0.y = fmaxf(fmaf(di, acc[1], bb0.y), 0.f);
    o0.z = fmaxf(fmaf(di, acc[2], bb0.z), 0.f);
    o0.w = fmaxf(fmaf(di, acc[3], bb0.w), 0.f);
    o1.x = fmaxf(fmaf(di, acc[4], bb1.x), 0.f);
    o1.y = fmaxf(fmaf(di, acc[5], bb1.y), 0.f);
    o1.z = fmaxf(fmaf(di, acc[6], bb1.z), 0.f);
    o1.w = fmaxf(fmaf(di, acc[7], bb1.w), 0.f);
    float4* o4 = (float4*)out;              // one row = 32 float4
    o4[(size_t)node * 32 + li * 2] = o0;
    o4[(size_t)node * 32 + li * 2 + 1] = o1;
}

// ---------------- fp32 fallback (small ws): atomic scatter ----------------

__global__ void k_count_plain(const int* dst, int* cnt, int e) {
    int i = blockIdx.x * blockDim.x + threadIdx.x;
    if (i < e) atomicAdd(&cnt[dst[i]], 1);
}

__global__ void k_dinv_only(const int* cnt, float* dinv, int n) {
    int i = blockIdx.x * blockDim.x + threadIdx.x;
    if (i < n) dinv[i] = rsqrtf((float)(cnt[i] + 1));
}

__global__ void k_self(const float* x, const float* dinv, float* out, int n) {
    int gid = blockIdx.x * blockDim.x + threadIdx.x;
    if (gid < n * 32) {
        int row = gid >> 5;
        float di = dinv[row];
        float w0 = di * di;
        float4 v = ((const float4*)x)[gid];
        v.x *= w0; v.y *= w0; v.z *= w0; v.w *= w0;
        ((float4*)out)[gid] = v;
    }
}

__global__ void k_scatter_atomic(const float* x, const int* src, const int* dst,
                                 const float* dinv, float* out, int e) {
    int gid = blockIdx.x * blockDim.x + threadIdx.x;
    int eid = gid >> 5, q = gid & 31;
    if (eid >= e) return;
    int s = src[eid], d = dst[eid];
    float c = dinv[s] * dinv[d];
    float4 v = ((const float4*)x)[(size_t)s * 32 + q];
    float* o = out + (size_t)d * D + q * 4;
    atomicAdd(o + 0, c * v.x);
    atomicAdd(o + 1, c * v.y);
    atomicAdd(o + 2, c * v.z);
    atomicAdd(o + 3, c * v.w);
}

__global__ __launch_bounds__(512) void k_gemm_relu(float* io, const float* W,
                                                   const float* b, int n) {
    __shared__ float4 Wl[D * 32];
    int t = threadIdx.x;
    const float4* W4 = (const float4*)W;
#pragma unroll
    for (int q = 0; q < 8; ++q) Wl[t + q * 512] = W4[t + q * 512];
    __syncthreads();
    int tx = t & 31, ty = t >> 5;
    int row0 = blockIdx.x * 128;
    const float4* a4 = (const float4*)io;
    int rb[8];
#pragma unroll
    for (int r = 0; r < 8; ++r) {
        int gr = row0 + ty * 8 + r;
        if (gr > n - 1) gr = n - 1;
        rb[r] = gr * 32;
    }
    float4 bb = ((const float4*)b)[tx];
    float4 acc[8];
#pragma unroll
    for (int r = 0; r < 8; ++r) acc[r] = bb;
    for (int k4 = 0; k4 < 32; ++k4) {
        float4 a[8];
#pragma unroll
        for (int r = 0; r < 8; ++r) a[r] = a4[(size_t)rb[r] + k4];
#pragma unroll
        for (int kk = 0; kk < 4; ++kk) {
            float4 w = Wl[(k4 * 4 + kk) * 32 + tx];
#pragma unroll
            for (int r = 0; r < 8; ++r) {
                float av = (kk == 0) ? a[r].x : (kk == 1) ? a[r].y
                           : (kk == 2) ? a[r].z : a[r].w;
                acc[r].x += av * w.x;
                acc[r].y += av * w.y;
                acc[r].z += av * w.z;
                acc[r].w += av * w.w;
            }
        }
    }
    __syncthreads();
    float4* o4 = (float4*)io;
#pragma unroll
    for (int r = 0; r < 8; ++r) {
        int gr = row0 + ty * 8 + r;
        if (gr < n) {
            float4 v = acc[r];
            v.x = fmaxf(v.x, 0.f); v.y = fmaxf(v.y, 0.f);
            v.z = fmaxf(v.z, 0.f); v.w = fmaxf(v.w, 0.f);
            o4[(size_t)gr * 32 + tx] = v;
        }
    }
}

// ---------------- launch ----------------

extern "C" void kernel_launch(void* const* d_in, const int* in_sizes, int n_in,
                              void* d_out, int out_size, void* d_ws, size_t ws_size,
                              hipStream_t stream) {
    const float* x = (const float*)d_in[0];
    const int* ei = (const int*)d_in[1];
    const float* W = (const float*)d_in[2];
    const float* b = (const float*)d_in[3];
    float* out = (float*)d_out;

    int n = in_sizes[0] / D;
    int e = in_sizes[1] / 2;
    const int* src = ei;
    const int* dst = ei + e;

    char* ws = (char*)d_ws;
    size_t nB = (size_t)n * 4;
    size_t o_cnt = 0;
    size_t o_off = nB;
    size_t o_dinv = 2 * nB;
    size_t o_bsum = 3 * nB;                       // 2 KB
    size_t o_bscan = 3 * nB + 2048;               // 2 KB
    size_t o_slot = 3 * nB + 4096;
    size_t o_ssrc2 = (o_slot + (size_t)e * 4 + 15) & ~(size_t)15;
    size_t o_h = (o_ssrc2 + (size_t)e * 8 + 15) & ~(size_t)15;
    size_t need = o_h + (size_t)n * D * 2;

    int* cnt    = (int*)(ws + o_cnt);
    int* off    = (int*)(ws + o_off);
    float* dinv = (float*)(ws + o_dinv);
    int* bsum   = (int*)(ws + o_bsum);
    int* bscan  = (int*)(ws + o_bscan);
    int* slot   = (int*)(ws + o_slot);
    int2* ssrc2 = (int2*)(ws + o_ssrc2);
    unsigned short* h = (unsigned short*)(ws + o_h);

    int nb2 = (n + 511) / 512;                    // scan blocks (512 nodes each)
    int gb = (n + 127) / 128;                     // gemm blocks (128 rows each)
    int n4 = (n + 3) / 4;
    int pre0 = (n4 + 511) / 512;                  // init blocks
    // int4 paths need e%4==0 and 16B-aligned src/dst (dst = ei + e)
    bool vec4 = ((e & 3) == 0) && ((((uintptr_t)ei) & 15) == 0) && (((e * 4) & 15) == 0);

    if (ws_size >= need && nb2 <= NB2MAX) {
        // split gemm across the 4 preproc launches (stage hides under HBM-bound gemm)
        int g1 = gb < 160 ? gb : 160;
        int rem = gb - g1;
        int g2 = rem < 250 ? rem : 250; rem -= g2;
        int g3 = rem < 190 ? rem : 190; rem -= g3;
        int g4 = rem;

        if (vec4) {
            int e4 = e >> 2;
            int pre1 = (e4 + 511) / 512;
            k_stage<<<pre0 + g1, 512, 0, stream>>>(0, pre0, 0, n,
                cnt, slot, dst, off, bsum, dinv, bscan, nb2, x, W, h, n);
            k_stage<<<pre1 + g2, 512, 0, stream>>>(1, pre1, g1, e4,
                cnt, slot, dst, off, bsum, dinv, bscan, nb2, x, W, h, n);
            k_stage<<<nb2 + g3, 512, 0, stream>>>(2, nb2, g1 + g2, n,
                cnt, slot, dst, off, bsum, dinv, bscan, nb2, x, W, h, n);
            k_stage<<<1 + g4, 512, 0, stream>>>(3, 1, g1 + g2 + g3, 0,
                cnt, slot, dst, off, bsum, dinv, bscan, nb2, x, W, h, n);
            k_permw_v4<<<pre1, 512, 0, stream>>>(src, dst, off, bscan, slot, dinv, ssrc2, e4);
        } else {
            int eb = (e + 255) / 256;
            k_stage<<<pre0 + gb, 512, 0, stream>>>(0, pre0, 0, n,
                cnt, slot, dst, off, bsum, dinv, bscan, nb2, x, W, h, n);
            k_count_s<<<eb, 256, 0, stream>>>(dst, cnt, slot, e);
            k_stage<<<nb2, 512, 0, stream>>>(2, nb2, 0, n,
                cnt, slot, dst, off, bsum, dinv, bscan, nb2, x, W, h, n);
            k_stage<<<1, 512, 0, stream>>>(3, 1, 0, 0,
                cnt, slot, dst, off, bsum, dinv, bscan, nb2, x, W, h, n);
            k_permw_s<<<eb, 256, 0, stream>>>(src, dst, off, bscan, slot, dinv, ssrc2, e);
        }
        int gblocks = ((size_t)n * 16 + 255) / 256;
        k_gather4<<<gblocks, 256, 0, stream>>>(h, dinv, off, cnt, bscan, ssrc2, b, out, n);
    } else {
        // fp32 atomic-scatter fallback (needs only ~1.2 MB ws)
        int nb = (n + 255) / 256;
        int eb = (e + 255) / 256;
        float* dinv2 = (float*)(ws + nB);
        k_stage<<<pre0, 512, 0, stream>>>(0, pre0, 0, n,
            cnt, (int*)(ws + 2 * nB), dst, (int*)(ws + 2 * nB), (int*)(ws + 2 * nB),
            dinv2, (int*)(ws + 2 * nB), 1, x, W, (unsigned short*)(ws + 2 * nB), n);
        k_count_plain<<<eb, 256, 0, stream>>>(dst, cnt, e);
        k_dinv_only<<<nb, 256, 0, stream>>>(cnt, dinv2, n);
        k_self<<<(n * 32 + 255) / 256, 256, 0, stream>>>(x, dinv2, out, n);
        k_scatter_atomic<<<((size_t)e * 32 + 255) / 256, 256, 0, stream>>>(
            x, src, dst, dinv2, out, e);
        k_gemm_relu<<<(n + 127) / 128, 512, 0, stream>>>(out, W, b, n);
    }
}